// Round 1
// baseline (293.916 us; speedup 1.0000x reference)
//
#include <hip/hip_runtime.h>
#include <hip/hip_bf16.h>
#include <math.h>

#define B_ 64
#define S_ 512
#define VEC_ 768
#define H_ 256
#define M_ (B_*S_)   // 32768

typedef float floatx4 __attribute__((ext_vector_type(4)));
typedef __bf16 bf16x8 __attribute__((ext_vector_type(8)));
typedef __bf16 bf16x4 __attribute__((ext_vector_type(4)));

// prep: cast mlp_w (f32 [256,768]) -> bf16, zero doc-sum accumulators
__global__ __launch_bounds__(256) void prep_kernel(
    const float* __restrict__ mlp_w, __bf16* __restrict__ wbf, float* __restrict__ sums)
{
  const int bid = blockIdx.x;
  if (bid < 192) {
    const int i = bid * 256 + threadIdx.x;           // float4 index, 49152 total
    const float4 v = ((const float4*)mlp_w)[i];
    bf16x4 b = { (__bf16)v.x, (__bf16)v.y, (__bf16)v.z, (__bf16)v.w };
    *(bf16x4*)&wbf[(size_t)i * 4] = b;
  } else {
    const int i = (bid - 192) * 256 + threadIdx.x;   // 8192 float4 = 2*64*256 f32
    ((float4*)sums)[i] = make_float4(0.f, 0.f, 0.f, 0.f);
  }
}

// ---------------- GEMM: m97-structure port ----------------
// LDS layout per buffer: A f32 [128][32] (16 KB, source-swizzled cc^=row&7 on 16B chunks)
//                        B bf16 [128][32] (8 KB,  source-swizzled cc^=(row^row>>2)&3)
// global_load_lds width-16 direct staging (linear dest), double-buffered, 1 barrier/K-step.
#define ABUF_ 16384
#define BUFB_ 24576
#define LDSB_ 49152

__device__ __forceinline__ void gl_lds16(char* l, const void* g) {
  __builtin_amdgcn_global_load_lds(
      (const __attribute__((address_space(1))) unsigned int*)g,
      (__attribute__((address_space(3))) unsigned int*)l, 16, 0, 0);
}

// stage tile (kk = k0 of tile) into buffer at byte offset bufbase
#define STAGE(bufbase, kk)                                                    \
  {                                                                           \
    _Pragma("unroll")                                                         \
    for (int i_ = 0; i_ < 4; i_++) {          /* A: 1024 x 16B chunks */      \
      const int ch = t + i_ * 256;                                            \
      const int row = ch >> 3;                                                \
      const int cc = (ch & 7) ^ (row & 7);    /* inverse swizzle on source */ \
      gl_lds16(smem + (bufbase) + ch * 16,                                    \
               Abase + (size_t)row * VEC_ + (kk) + cc * 4);                   \
    }                                                                         \
    _Pragma("unroll")                                                         \
    for (int i_ = 0; i_ < 2; i_++) {          /* B: 512 x 16B chunks */       \
      const int ch = t + i_ * 256;                                            \
      const int row = ch >> 2;                                                \
      const int cc = ((ch & 3) ^ row ^ (row >> 2)) & 3;                       \
      gl_lds16(smem + (bufbase) + ABUF_ + ch * 16,                            \
               Bbase + (size_t)row * VEC_ + (kk) + cc * 8);                   \
    }                                                                         \
  }

// read fragments (swizzled) + 16 MFMA from buffer at byte offset bufbase
#define COMPUTE(bufbase)                                                      \
  {                                                                           \
    const char* Ab = smem + (bufbase);                                        \
    const char* Bb = smem + (bufbase) + ABUF_;                                \
    bf16x8 af[4]; bf16x8 bfr[4];                                              \
    _Pragma("unroll")                                                         \
    for (int i = 0; i < 4; i++) {                                             \
      const int base = (wm + i * 16 + c) * 128;                               \
      const floatx4 a0 = *(const floatx4*)(Ab + base + aslot0);               \
      const floatx4 a1 = *(const floatx4*)(Ab + base + (aslot0 ^ 16));        \
      bf16x8 v;                                                               \
      v[0] = (__bf16)a0[0]; v[1] = (__bf16)a0[1];                             \
      v[2] = (__bf16)a0[2]; v[3] = (__bf16)a0[3];                             \
      v[4] = (__bf16)a1[0]; v[5] = (__bf16)a1[1];                             \
      v[6] = (__bf16)a1[2]; v[7] = (__bf16)a1[3];                             \
      af[i] = v;                                                              \
    }                                                                         \
    _Pragma("unroll")                                                         \
    for (int j = 0; j < 4; j++)                                               \
      bfr[j] = *(const bf16x8*)(Bb + (wn + j * 16 + c) * 64 + bslot);         \
    _Pragma("unroll")                                                         \
    for (int i = 0; i < 4; i++)                                               \
      _Pragma("unroll")                                                       \
      for (int j = 0; j < 4; j++)                                             \
        acc[i][j] = __builtin_amdgcn_mfma_f32_16x16x32_bf16(af[i], bfr[j],    \
                                                            acc[i][j], 0, 0, 0); \
  }

__global__ __launch_bounds__(256, 3) void gemm_doc_kernel(
    const float* __restrict__ out1, const float* __restrict__ out2,
    const __bf16* __restrict__ wbf, const float* __restrict__ mlp_b,
    __bf16* __restrict__ o1, float* __restrict__ sum1, float* __restrict__ sum2)
{
  __shared__ __align__(16) char smem[LDSB_];

  const int tensor = blockIdx.z;
  const float* __restrict__ A = tensor ? out2 : out1;
  float* __restrict__ dsum = tensor ? sum2 : sum1;

  const int n0 = blockIdx.x * 128;
  const int m0 = blockIdx.y * 128;
  const int bidx = m0 >> 9;  // 512 rows per doc; tiles never straddle docs

  const int t = threadIdx.x;
  const int lane = t & 63;
  const int wave = t >> 6;
  const int q = lane >> 4;
  const int c = lane & 15;
  const int wm = (wave >> 1) * 64;
  const int wn = (wave & 1) * 64;

  // fragment-read swizzled slot offsets (uniform over i/j since wm,wn,i*16 are mult of 16)
  const int aslot0 = (((2 * q) ^ (c & 7)) << 4);          // A: 16B slot, second half = ^16
  const int bslot  = (((q ^ c ^ (c >> 2)) & 3) << 4);     // B: 16B slot within 64B row

  const float* Abase = &A[(size_t)m0 * VEC_];
  const __bf16* Bbase = &wbf[(size_t)n0 * VEC_];

  floatx4 acc[4][4];
#pragma unroll
  for (int i = 0; i < 4; i++)
#pragma unroll
    for (int j = 0; j < 4; j++)
      acc[i][j] = (floatx4){0.f, 0.f, 0.f, 0.f};

  // prologue: stage tile 0
  STAGE(0, 0);
  __syncthreads();

  int bufb = 0;
  int kk = 32;
#pragma unroll 1
  for (int kt = 0; kt < 23; ++kt) {
    STAGE(bufb ^ BUFB_, kk);   // issue next-tile loads first (in flight during compute)
    COMPUTE(bufb);
    kk += 32;
    __syncthreads();           // drains vmcnt+lgkmcnt, publishes staged tile
    bufb ^= BUFB_;
  }
  COMPUTE(bufb);               // last tile, no stage

  // epilogue: bias + relu, store bf16 (tensor 0), column sums -> atomicAdd doc sums
#pragma unroll
  for (int j = 0; j < 4; j++) {
    const int n = n0 + wn + j * 16 + c;
    const float bias = mlp_b[n];
    float colsum = 0.f;
#pragma unroll
    for (int i = 0; i < 4; i++) {
      const int mbase = m0 + wm + i * 16 + q * 4;
#pragma unroll
      for (int r = 0; r < 4; r++) {
        float v = acc[i][j][r] + bias;
        v = fmaxf(v, 0.f);
        colsum += v;
        if (tensor == 0) o1[(size_t)(mbase + r) * H_ + n] = (__bf16)v;
      }
    }
    colsum += __shfl_down(colsum, 32);
    colsum += __shfl_down(colsum, 16);
    if (lane < 16)
      atomicAdd(&dsum[bidx * H_ + n0 + wn + j * 16 + lane], colsum);
  }
}

// logits: one s-row per wave. grid (129, B): s = bx*4+wave, rows 0..511 from o1,
// row 512 from o1_doc. lg[b,s] = dot(o1_row, o2_doc)
__global__ __launch_bounds__(256) void logits_kernel(
    const __bf16* __restrict__ o1, const float* __restrict__ sum1,
    const float* __restrict__ sum2, float* __restrict__ lg)
{
  const int b = blockIdx.y;
  const int t = threadIdx.x, lane = t & 63, wave = t >> 6;
  const int s = blockIdx.x * 4 + wave;
  if (s > 512) return;
  const float sc = 1.f / 512.f;
  const float4 w4 = ((const float4*)&sum2[b * H_])[lane];
  float p;
  if (s < 512) {
    const bf16x4 x = ((const bf16x4*)&o1[((size_t)b * S_ + s) * H_])[lane];
    p = ((float)x[0] * w4.x + (float)x[1] * w4.y +
         (float)x[2] * w4.z + (float)x[3] * w4.w) * sc;
  } else {
    const float4 x = ((const float4*)&sum1[b * H_])[lane];
    p = (x.x * w4.x + x.y * w4.y + x.z * w4.z + x.w * w4.w) * sc * sc;
  }
  p += __shfl_down(p, 32); p += __shfl_down(p, 16); p += __shfl_down(p, 8);
  p += __shfl_down(p, 4);  p += __shfl_down(p, 2);  p += __shfl_down(p, 1);
  if (lane == 0) lg[b * 513 + s] = p;
}

// fused: MLP head (row 512 of att) + softmax over 513 logits (rows 0..511)
__global__ __launch_bounds__(256) void softmax_head_kernel(
    const float* __restrict__ lg, const float* __restrict__ sum1, const float* __restrict__ sum2,
    const float* __restrict__ fd_w, const float* __restrict__ fd_b,
    const float* __restrict__ ff_w, const float* __restrict__ ff_b,
    float* __restrict__ out)
{
  const int b = blockIdx.x, t = threadIdx.x, lane = t & 63, wave = t >> 6;
  __shared__ __align__(16) float dc[512];
  __shared__ float sl[513];
  __shared__ float red[4], r1[4], r2[4];

  // --- head: h = relu(fd_w @ cat(o1_doc,o2_doc) + fd_b); out[512,b] = sigmoid(ff_w.h + ff_b)
  dc[t]       = sum1[b * H_ + t] * (1.f / 512.f);
  dc[t + 256] = sum2[b * H_ + t] * (1.f / 512.f);
  for (int i = t; i < 513; i += 256) sl[i] = lg[b * 513 + i];
  __syncthreads();
  const float4* wrow = (const float4*)&fd_w[(size_t)t * 512];
  const float4* dc4  = (const float4*)dc;
  float a0 = 0.f, a1 = 0.f;
#pragma unroll 8
  for (int k = 0; k < 128; k += 2) {
    const float4 w0 = wrow[k],     d0 = dc4[k];
    const float4 w1 = wrow[k + 1], d1 = dc4[k + 1];
    a0 += w0.x * d0.x + w0.y * d0.y + w0.z * d0.z + w0.w * d0.w;
    a1 += w1.x * d1.x + w1.y * d1.y + w1.z * d1.z + w1.w * d1.w;
  }
  const float h = fmaxf(a0 + a1 + fd_b[t], 0.f);
  float part = ff_w[t] * h;
  part += __shfl_down(part, 32); part += __shfl_down(part, 16);
  part += __shfl_down(part, 8);  part += __shfl_down(part, 4);
  part += __shfl_down(part, 2);  part += __shfl_down(part, 1);
  if (lane == 0) red[wave] = part;

  // --- softmax over sl[0..512]
  float m = -1e30f;
  for (int i = t; i < 513; i += 256) m = fmaxf(m, sl[i]);
  m = fmaxf(m, __shfl_down(m, 32)); m = fmaxf(m, __shfl_down(m, 16));
  m = fmaxf(m, __shfl_down(m, 8));  m = fmaxf(m, __shfl_down(m, 4));
  m = fmaxf(m, __shfl_down(m, 2));  m = fmaxf(m, __shfl_down(m, 1));
  if (lane == 0) r1[wave] = m;
  __syncthreads();
  m = fmaxf(fmaxf(r1[0], r1[1]), fmaxf(r1[2], r1[3]));
  float psum = 0.f;
  for (int i = t; i < 513; i += 256) { const float e = expf(sl[i] - m); sl[i] = e; psum += e; }
  psum += __shfl_down(psum, 32); psum += __shfl_down(psum, 16); psum += __shfl_down(psum, 8);
  psum += __shfl_down(psum, 4);  psum += __shfl_down(psum, 2);  psum += __shfl_down(psum, 1);
  if (lane == 0) r2[wave] = psum;
  __syncthreads();
  const float inv = 1.f / (r2[0] + r2[1] + r2[2] + r2[3]);
  for (int s = t; s < 512; s += 256) out[s * 64 + b] = sl[s] * inv;
  if (t == 0) {
    const float tot = red[0] + red[1] + red[2] + red[3] + ff_b[0];
    out[(size_t)512 * 64 + b] = 1.f / (1.f + expf(-tot));
  }
}

extern "C" void kernel_launch(void* const* d_in, const int* in_sizes, int n_in,
                              void* d_out, int out_size, void* d_ws, size_t ws_size,
                              hipStream_t stream) {
  const float* out1  = (const float*)d_in[0];
  const float* out2  = (const float*)d_in[1];
  const float* mlp_w = (const float*)d_in[2];
  const float* mlp_b = (const float*)d_in[3];
  const float* fd_w  = (const float*)d_in[4];
  const float* fd_b  = (const float*)d_in[5];
  const float* ff_w  = (const float*)d_in[6];
  const float* ff_b  = (const float*)d_in[7];
  float* out = (float*)d_out;

  __bf16* o1  = (__bf16*)d_ws;                       // 32768*256 bf16 = 16.78 MB
  __bf16* wbf = o1 + (size_t)M_ * H_;                // 256*768 bf16
  float*  s1  = (float*)(wbf + (size_t)H_ * VEC_);   // 64*256 f32
  float*  s2  = s1 + B_ * H_;                        // 64*256 f32
  float*  lgw = s2 + B_ * H_;                        // 64*513 f32

  prep_kernel<<<224, 256, 0, stream>>>(mlp_w, wbf, s1);
  gemm_doc_kernel<<<dim3(2, 256, 2), 256, 0, stream>>>(out1, out2, wbf, mlp_b, o1, s1, s2);
  logits_kernel<<<dim3(129, B_), 256, 0, stream>>>(o1, s1, s2, lgw);
  softmax_head_kernel<<<B_, 256, 0, stream>>>(lgw, s1, s2, fd_w, fd_b, ff_w, ff_b, out);
}

// Round 2
// 285.998 us; speedup vs baseline: 1.0277x; 1.0277x over previous
//
#include <hip/hip_runtime.h>
#include <hip/hip_bf16.h>
#include <math.h>

#define B_ 64
#define S_ 512
#define VEC_ 768
#define H_ 256
#define M_ (B_*S_)   // 32768

typedef float floatx4 __attribute__((ext_vector_type(4)));
typedef __bf16 bf16x8 __attribute__((ext_vector_type(8)));
typedef __bf16 bf16x4 __attribute__((ext_vector_type(4)));

// prep: cast mlp_w (f32 [256,768]) -> bf16, zero doc-sum accumulators
__global__ __launch_bounds__(256) void prep_kernel(
    const float* __restrict__ mlp_w, __bf16* __restrict__ wbf, float* __restrict__ sums)
{
  const int bid = blockIdx.x;
  if (bid < 192) {
    const int i = bid * 256 + threadIdx.x;           // float4 index, 49152 total
    const float4 v = ((const float4*)mlp_w)[i];
    bf16x4 b = { (__bf16)v.x, (__bf16)v.y, (__bf16)v.z, (__bf16)v.w };
    *(bf16x4*)&wbf[(size_t)i * 4] = b;
  } else {
    const int i = (bid - 192) * 256 + threadIdx.x;   // 8192 float4 = 2*64*256 f32
    ((float4*)sums)[i] = make_float4(0.f, 0.f, 0.f, 0.f);
  }
}

// ---------------- GEMM: 3-buffer counted-vmcnt pipeline (T3+T4) ----------------
// Per buffer: A f32 [128][32] (16 KB, source-swizzled) + B bf16 [128][32] (8 KB).
// 3 buffers x 24 KB = 72 KB LDS. 2 tiles always in HBM flight per wave; the main
// loop NEVER drains vmcnt to 0 — raw s_barrier + asm s_waitcnt vmcnt(6).
#define ABUF_  16384
#define BUFSZ_ 24576
#define LDSB_  73728

__device__ __forceinline__ void gl_lds16(char* l, const void* g) {
  __builtin_amdgcn_global_load_lds(
      (const __attribute__((address_space(1))) unsigned int*)g,
      (__attribute__((address_space(3))) unsigned int*)l, 16, 0, 0);
}

// stage tile (kk = k0 of tile) into buffer at byte offset bufbase (6 loads/thread)
#define STAGE(bufbase, kk)                                                    \
  {                                                                           \
    _Pragma("unroll")                                                         \
    for (int i_ = 0; i_ < 4; i_++) {          /* A: 1024 x 16B chunks */      \
      const int ch = t + i_ * 256;                                            \
      const int row = ch >> 3;                                                \
      const int cc = (ch & 7) ^ (row & 7);    /* inverse swizzle on source */ \
      gl_lds16(smem + (bufbase) + ch * 16,                                    \
               Abase + (size_t)row * VEC_ + (kk) + cc * 4);                   \
    }                                                                         \
    _Pragma("unroll")                                                         \
    for (int i_ = 0; i_ < 2; i_++) {          /* B: 512 x 16B chunks */       \
      const int ch = t + i_ * 256;                                            \
      const int row = ch >> 2;                                                \
      const int cc = ((ch & 3) ^ row ^ (row >> 2)) & 3;                       \
      gl_lds16(smem + (bufbase) + ABUF_ + ch * 16,                            \
               Bbase + (size_t)row * VEC_ + (kk) + cc * 8);                   \
    }                                                                         \
  }

// read fragments (swizzled) + 16 MFMA from buffer at byte offset bufbase
#define COMPUTE(bufbase)                                                      \
  {                                                                           \
    const char* Ab = smem + (bufbase);                                        \
    const char* Bb = smem + (bufbase) + ABUF_;                                \
    bf16x8 af[4]; bf16x8 bfr[4];                                              \
    _Pragma("unroll")                                                         \
    for (int i = 0; i < 4; i++) {                                             \
      const int base = (wm + i * 16 + c) * 128;                               \
      const floatx4 a0 = *(const floatx4*)(Ab + base + aslot0);               \
      const floatx4 a1 = *(const floatx4*)(Ab + base + (aslot0 ^ 16));        \
      bf16x8 v;                                                               \
      v[0] = (__bf16)a0[0]; v[1] = (__bf16)a0[1];                             \
      v[2] = (__bf16)a0[2]; v[3] = (__bf16)a0[3];                             \
      v[4] = (__bf16)a1[0]; v[5] = (__bf16)a1[1];                             \
      v[6] = (__bf16)a1[2]; v[7] = (__bf16)a1[3];                             \
      af[i] = v;                                                              \
    }                                                                         \
    _Pragma("unroll")                                                         \
    for (int j = 0; j < 4; j++)                                               \
      bfr[j] = *(const bf16x8*)(Bb + (wn + j * 16 + c) * 64 + bslot);         \
    _Pragma("unroll")                                                         \
    for (int i = 0; i < 4; i++)                                               \
      _Pragma("unroll")                                                       \
      for (int j = 0; j < 4; j++)                                             \
        acc[i][j] = __builtin_amdgcn_mfma_f32_16x16x32_bf16(af[i], bfr[j],    \
                                                            acc[i][j], 0, 0, 0); \
  }

__global__ __launch_bounds__(256, 2) void gemm_doc_kernel(
    const float* __restrict__ out1, const float* __restrict__ out2,
    const __bf16* __restrict__ wbf, const float* __restrict__ mlp_b,
    __bf16* __restrict__ o1, float* __restrict__ sum1, float* __restrict__ sum2)
{
  __shared__ __align__(16) char smem[LDSB_];

  const int tensor = blockIdx.z;
  const float* __restrict__ A = tensor ? out2 : out1;
  float* __restrict__ dsum = tensor ? sum2 : sum1;

  const int n0 = blockIdx.x * 128;
  const int m0 = blockIdx.y * 128;
  const int bidx = m0 >> 9;  // 512 rows per doc; tiles never straddle docs

  const int t = threadIdx.x;
  const int lane = t & 63;
  const int wave = t >> 6;
  const int q = lane >> 4;
  const int c = lane & 15;
  const int wm = (wave >> 1) * 64;
  const int wn = (wave & 1) * 64;

  // fragment-read swizzled slot offsets (uniform over i/j since wm,wn,i*16 are mult of 16)
  const int aslot0 = (((2 * q) ^ (c & 7)) << 4);          // A: 16B slot, second half = ^16
  const int bslot  = (((q ^ c ^ (c >> 2)) & 3) << 4);     // B: 16B slot within 64B row

  const float* Abase = &A[(size_t)m0 * VEC_];
  const __bf16* Bbase = &wbf[(size_t)n0 * VEC_];

  floatx4 acc[4][4];
#pragma unroll
  for (int i = 0; i < 4; i++)
#pragma unroll
    for (int j = 0; j < 4; j++)
      acc[i][j] = (floatx4){0.f, 0.f, 0.f, 0.f};

  // prologue: 2 tiles in flight before the first wait
  STAGE(0, 0);
  STAGE(BUFSZ_, 32);

  // Main loop: 24 K-steps total. Steady state per wave: 12 loads outstanding
  // (tiles kt, kt+1). s_waitcnt vmcnt(6) retires exactly tile kt; the barrier
  // then publishes it AND certifies buf[(kt+2)%3] (tile kt-1) is done being read.
  int cb = 0;            // compute-buffer byte offset, (kt)%3
  int sb = 2 * BUFSZ_;   // stage-buffer byte offset, (kt+2)%3
#pragma unroll 1
  for (int kt = 0; kt < 23; ++kt) {
    asm volatile("s_waitcnt vmcnt(6)" ::: "memory");
    __builtin_amdgcn_s_barrier();
    if (kt < 22) STAGE(sb, (kt + 2) * 32);   // keep 2 tiles in flight
    COMPUTE(cb);
    cb += BUFSZ_; if (cb == 3 * BUFSZ_) cb = 0;
    sb += BUFSZ_; if (sb == 3 * BUFSZ_) sb = 0;
  }
  // epilogue: only tile 23's 6 loads remain
  asm volatile("s_waitcnt vmcnt(0)" ::: "memory");
  __builtin_amdgcn_s_barrier();
  COMPUTE(cb);

  // epilogue: bias + relu, store bf16 (tensor 0), column sums -> atomicAdd doc sums
#pragma unroll
  for (int j = 0; j < 4; j++) {
    const int n = n0 + wn + j * 16 + c;
    const float bias = mlp_b[n];
    float colsum = 0.f;
#pragma unroll
    for (int i = 0; i < 4; i++) {
      const int mbase = m0 + wm + i * 16 + q * 4;
#pragma unroll
      for (int r = 0; r < 4; r++) {
        float v = acc[i][j][r] + bias;
        v = fmaxf(v, 0.f);
        colsum += v;
        if (tensor == 0) o1[(size_t)(mbase + r) * H_ + n] = (__bf16)v;
      }
    }
    colsum += __shfl_down(colsum, 32);
    colsum += __shfl_down(colsum, 16);
    if (lane < 16)
      atomicAdd(&dsum[bidx * H_ + n0 + wn + j * 16 + lane], colsum);
  }
}

// logits: one s-row per wave. grid (129, B): s = bx*4+wave, rows 0..511 from o1,
// row 512 from o1_doc. lg[b,s] = dot(o1_row, o2_doc)
__global__ __launch_bounds__(256) void logits_kernel(
    const __bf16* __restrict__ o1, const float* __restrict__ sum1,
    const float* __restrict__ sum2, float* __restrict__ lg)
{
  const int b = blockIdx.y;
  const int t = threadIdx.x, lane = t & 63, wave = t >> 6;
  const int s = blockIdx.x * 4 + wave;
  if (s > 512) return;
  const float sc = 1.f / 512.f;
  const float4 w4 = ((const float4*)&sum2[b * H_])[lane];
  float p;
  if (s < 512) {
    const bf16x4 x = ((const bf16x4*)&o1[((size_t)b * S_ + s) * H_])[lane];
    p = ((float)x[0] * w4.x + (float)x[1] * w4.y +
         (float)x[2] * w4.z + (float)x[3] * w4.w) * sc;
  } else {
    const float4 x = ((const float4*)&sum1[b * H_])[lane];
    p = (x.x * w4.x + x.y * w4.y + x.z * w4.z + x.w * w4.w) * sc * sc;
  }
  p += __shfl_down(p, 32); p += __shfl_down(p, 16); p += __shfl_down(p, 8);
  p += __shfl_down(p, 4);  p += __shfl_down(p, 2);  p += __shfl_down(p, 1);
  if (lane == 0) lg[b * 513 + s] = p;
}

// fused: MLP head (row 512 of att) + softmax over 513 logits (rows 0..511)
__global__ __launch_bounds__(256) void softmax_head_kernel(
    const float* __restrict__ lg, const float* __restrict__ sum1, const float* __restrict__ sum2,
    const float* __restrict__ fd_w, const float* __restrict__ fd_b,
    const float* __restrict__ ff_w, const float* __restrict__ ff_b,
    float* __restrict__ out)
{
  const int b = blockIdx.x, t = threadIdx.x, lane = t & 63, wave = t >> 6;
  __shared__ __align__(16) float dc[512];
  __shared__ float sl[513];
  __shared__ float red[4], r1[4], r2[4];

  // --- head: h = relu(fd_w @ cat(o1_doc,o2_doc) + fd_b); out[512,b] = sigmoid(ff_w.h + ff_b)
  dc[t]       = sum1[b * H_ + t] * (1.f / 512.f);
  dc[t + 256] = sum2[b * H_ + t] * (1.f / 512.f);
  for (int i = t; i < 513; i += 256) sl[i] = lg[b * 513 + i];
  __syncthreads();
  const float4* wrow = (const float4*)&fd_w[(size_t)t * 512];
  const float4* dc4  = (const float4*)dc;
  float a0 = 0.f, a1 = 0.f;
#pragma unroll 8
  for (int k = 0; k < 128; k += 2) {
    const float4 w0 = wrow[k],     d0 = dc4[k];
    const float4 w1 = wrow[k + 1], d1 = dc4[k + 1];
    a0 += w0.x * d0.x + w0.y * d0.y + w0.z * d0.z + w0.w * d0.w;
    a1 += w1.x * d1.x + w1.y * d1.y + w1.z * d1.z + w1.w * d1.w;
  }
  const float h = fmaxf(a0 + a1 + fd_b[t], 0.f);
  float part = ff_w[t] * h;
  part += __shfl_down(part, 32); part += __shfl_down(part, 16);
  part += __shfl_down(part, 8);  part += __shfl_down(part, 4);
  part += __shfl_down(part, 2);  part += __shfl_down(part, 1);
  if (lane == 0) red[wave] = part;

  // --- softmax over sl[0..512]
  float m = -1e30f;
  for (int i = t; i < 513; i += 256) m = fmaxf(m, sl[i]);
  m = fmaxf(m, __shfl_down(m, 32)); m = fmaxf(m, __shfl_down(m, 16));
  m = fmaxf(m, __shfl_down(m, 8));  m = fmaxf(m, __shfl_down(m, 4));
  m = fmaxf(m, __shfl_down(m, 2));  m = fmaxf(m, __shfl_down(m, 1));
  if (lane == 0) r1[wave] = m;
  __syncthreads();
  m = fmaxf(fmaxf(r1[0], r1[1]), fmaxf(r1[2], r1[3]));
  float psum = 0.f;
  for (int i = t; i < 513; i += 256) { const float e = expf(sl[i] - m); sl[i] = e; psum += e; }
  psum += __shfl_down(psum, 32); psum += __shfl_down(psum, 16); psum += __shfl_down(psum, 8);
  psum += __shfl_down(psum, 4);  psum += __shfl_down(psum, 2);  psum += __shfl_down(psum, 1);
  if (lane == 0) r2[wave] = psum;
  __syncthreads();
  const float inv = 1.f / (r2[0] + r2[1] + r2[2] + r2[3]);
  for (int s = t; s < 512; s += 256) out[s * 64 + b] = sl[s] * inv;
  if (t == 0) {
    const float tot = red[0] + red[1] + red[2] + red[3] + ff_b[0];
    out[(size_t)512 * 64 + b] = 1.f / (1.f + expf(-tot));
  }
}

extern "C" void kernel_launch(void* const* d_in, const int* in_sizes, int n_in,
                              void* d_out, int out_size, void* d_ws, size_t ws_size,
                              hipStream_t stream) {
  const float* out1  = (const float*)d_in[0];
  const float* out2  = (const float*)d_in[1];
  const float* mlp_w = (const float*)d_in[2];
  const float* mlp_b = (const float*)d_in[3];
  const float* fd_w  = (const float*)d_in[4];
  const float* fd_b  = (const float*)d_in[5];
  const float* ff_w  = (const float*)d_in[6];
  const float* ff_b  = (const float*)d_in[7];
  float* out = (float*)d_out;

  __bf16* o1  = (__bf16*)d_ws;                       // 32768*256 bf16 = 16.78 MB
  __bf16* wbf = o1 + (size_t)M_ * H_;                // 256*768 bf16
  float*  s1  = (float*)(wbf + (size_t)H_ * VEC_);   // 64*256 f32
  float*  s2  = s1 + B_ * H_;                        // 64*256 f32
  float*  lgw = s2 + B_ * H_;                        // 64*513 f32

  prep_kernel<<<224, 256, 0, stream>>>(mlp_w, wbf, s1);
  gemm_doc_kernel<<<dim3(2, 256, 2), 256, 0, stream>>>(out1, out2, wbf, mlp_b, o1, s1, s2);
  logits_kernel<<<dim3(129, B_), 256, 0, stream>>>(o1, s1, s2, lgw);
  softmax_head_kernel<<<B_, 256, 0, stream>>>(lgw, s1, s2, fd_w, fd_b, ff_w, ff_b, out);
}